// Round 1
// baseline (58.304 us; speedup 1.0000x reference)
//
#include <hip/hip_runtime.h>
#include <hip/hip_bf16.h>

// AttentionDot: B=16, TQ=128, TK=8192, H=256, fp32 in/out.
// Flash-style split-K attention in f16 MFMA (32x32x16), fp32 accumulate.
// Main kernel: 256 blocks (b x 16 ksplits) x 512 thr; combine kernel merges splits.
// Workspace use: 16 MiB f16 partial ctx + 256 KiB fp32 (m,l)  (~16.3 MiB total).

typedef _Float16 half8 __attribute__((ext_vector_type(8)));
typedef float floatx16 __attribute__((ext_vector_type(16)));
typedef unsigned int u32;

#define NB 16
#define TQ 128
#define TK 8192
#define HD 256
#define KSPLIT 16
#define KEYS_PER_SPLIT (TK / KSPLIT) /* 512 */
#define KB 32
#define NSUB (KEYS_PER_SPLIT / KB)   /* 16 */

// LDS map (exactly 64 KiB):
//   K bufs: 2 x [32 k][256 h] f16, row 512B, byte-in-row = (2h)^((k&7)<<4)   @ 0, 16384
//   V bufs: 2 x [4 row=kk>>3][256 slot][8 kk&7] f16, slot = h^((h>>3)&7)^row @ 32768, 49152

__global__ __launch_bounds__(512, 2) void attn_main(
    const float* __restrict__ enc, const float* __restrict__ dec,
    _Float16* __restrict__ pctx, float* __restrict__ pml) {
  __shared__ __align__(16) unsigned char smem[65536];
  const int tid = threadIdx.x;
  const int lane = tid & 63, wave = tid >> 6;
  const int wq = wave & 3;   // q-tile 32 rows
  const int wh = wave >> 2;  // h half (0..1)
  const int l31 = lane & 31, g2 = lane >> 5;
  const int b = blockIdx.x >> 4, ks = blockIdx.x & 15;

  // ---- Q fragments in registers: qf[c] holds Q[q=l31][c*16 + g2*8 + j] ----
  half8 qf[16];
  {
    const float* qrow = dec + (size_t)(b * TQ + wq * 32 + l31) * HD;
#pragma unroll
    for (int c = 0; c < 16; ++c) {
      const float4* p4 = (const float4*)(qrow + c * 16 + g2 * 8);
      float4 x = p4[0], y = p4[1];
      half8 v;
      v[0] = (_Float16)x.x; v[1] = (_Float16)x.y; v[2] = (_Float16)x.z; v[3] = (_Float16)x.w;
      v[4] = (_Float16)y.x; v[5] = (_Float16)y.y; v[6] = (_Float16)y.z; v[7] = (_Float16)y.w;
      qf[c] = v;
    }
  }

  floatx16 ctx[4];
#pragma unroll
  for (int t = 0; t < 4; ++t)
#pragma unroll
    for (int i = 0; i < 16; ++i) ctx[t][i] = 0.f;
  float mrun = -1e30f, lrun = 0.f;

  const size_t keybase = (size_t)b * TK + (size_t)ks * KEYS_PER_SPLIT;

  // staging mapping: thread -> rows sr0..sr0+3, h cols sh0..sh0+3
  const int sh0 = (tid & 63) * 4;
  const int sr0 = (tid >> 6) * 4;
  const int srv = (tid >> 6) >> 1; // V row (kk>>3)
  const int sa = (tid >> 6) & 1;   // which 8B half of the 16B V slot

  float lv[4][4];

  auto LOAD = [&](int sc) {
#pragma unroll
    for (int j = 0; j < 4; ++j) {
      float4 t = *(const float4*)(enc + (keybase + (size_t)sc * KB + sr0 + j) * HD + sh0);
      lv[j][0] = t.x; lv[j][1] = t.y; lv[j][2] = t.z; lv[j][3] = t.w;
    }
  };

  auto WRITE = [&](int buf) {
    unsigned char* kb_ = smem + buf * 16384;
    unsigned char* vb_ = smem + 32768 + buf * 16384;
#pragma unroll
    for (int j = 0; j < 4; ++j) {
      int r = sr0 + j;
      u32 w0 = __builtin_bit_cast(u32, __builtin_amdgcn_cvt_pkrtz(lv[j][0], lv[j][1]));
      u32 w1 = __builtin_bit_cast(u32, __builtin_amdgcn_cvt_pkrtz(lv[j][2], lv[j][3]));
      *(uint2*)(kb_ + r * 512 + ((2 * sh0) ^ ((r & 7) << 4))) = make_uint2(w0, w1);
    }
#pragma unroll
    for (int u = 0; u < 4; ++u) {
      int h = sh0 + u;
      int slot = h ^ ((h >> 3) & 7) ^ srv;
      u32 w0 = __builtin_bit_cast(u32, __builtin_amdgcn_cvt_pkrtz(lv[0][u], lv[1][u]));
      u32 w1 = __builtin_bit_cast(u32, __builtin_amdgcn_cvt_pkrtz(lv[2][u], lv[3][u]));
      *(uint2*)(vb_ + srv * 4096 + slot * 16 + 8 * sa) = make_uint2(w0, w1);
    }
  };

  auto COMPUTE = [&](int buf) {
    const unsigned char* kb_ = smem + buf * 16384;
    const unsigned char* vb_ = smem + 32768 + buf * 16384;
    // ---- GEMM1: S^T[kk, q] = K . Q^T  (A = K tile rows = l31, B = Q regs) ----
    floatx16 S;
#pragma unroll
    for (int i = 0; i < 16; ++i) S[i] = 0.f;
    const int krow = l31 * 512;
    const int kx = (l31 & 7) << 4;
#pragma unroll
    for (int c = 0; c < 16; ++c) {
      half8 a = *(const half8*)(kb_ + krow + ((c * 32 + g2 * 16) ^ kx));
      S = __builtin_amdgcn_mfma_f32_32x32x16_f16(a, qf[c], S, 0, 0, 0);
    }
    // ---- online softmax, lane owns q = l31; kk = (i&3)+8*(i>>2)+4*g2 ----
    float lmax = S[0];
#pragma unroll
    for (int i = 1; i < 16; ++i) lmax = fmaxf(lmax, S[i]);
    lmax = fmaxf(lmax, __shfl_xor(lmax, 32));
    if (__any(lmax > mrun + 8.f)) { // defer-max (T13)
      float mn = fmaxf(mrun, lmax);
      float al = __expf(mrun - mn);
      lrun *= al;
      mrun = mn;
#pragma unroll
      for (int i = 0; i < 16; ++i) {
        int qn = (i & 3) + 8 * (i >> 2) + 4 * g2;
        float aq = __shfl(al, qn);
#pragma unroll
        for (int t = 0; t < 4; ++t) ctx[t][i] *= aq;
      }
    }
    float p[16];
    float rs = 0.f;
#pragma unroll
    for (int i = 0; i < 16; ++i) {
      p[i] = __expf(S[i] - mrun);
      rs += p[i];
    }
    rs += __shfl_xor(rs, 32);
    lrun += rs;
    // ---- pack P to f16 and assemble PV A-fragments in-register ----
    u32 ph[8];
#pragma unroll
    for (int k2 = 0; k2 < 8; ++k2)
      ph[k2] = __builtin_bit_cast(u32, __builtin_amdgcn_cvt_pkrtz(p[2 * k2], p[2 * k2 + 1]));
#pragma unroll
    for (int c = 0; c < 2; ++c) {
      // own-needed pair and pair the partner needs (exchanged via lane^32)
      u32 a0 = ph[4 * c + 2 * g2], a1 = ph[4 * c + 2 * g2 + 1];
      u32 t0 = ph[4 * c + 2 * (1 - g2)], t1 = ph[4 * c + 2 * (1 - g2) + 1];
      u32 r0 = (u32)__shfl_xor((int)t0, 32);
      u32 r1 = (u32)__shfl_xor((int)t1, 32);
      union { u32 u[4]; half8 h8; } pf;
      if (g2 == 0) { pf.u[0] = a0; pf.u[1] = a1; pf.u[2] = r0; pf.u[3] = r1; }
      else         { pf.u[0] = r0; pf.u[1] = r1; pf.u[2] = a0; pf.u[3] = a1; }
      const int vrow = 2 * c + g2;
      const unsigned char* vr = vb_ + vrow * 4096;
#pragma unroll
      for (int ht = 0; ht < 4; ++ht) {
        int h = wh * 128 + ht * 32 + l31;
        int slot = h ^ ((h >> 3) & 7) ^ vrow;
        half8 vf = *(const half8*)(vr + slot * 16);
        ctx[ht] = __builtin_amdgcn_mfma_f32_32x32x16_f16(pf.h8, vf, ctx[ht], 0, 0, 0);
      }
    }
  };

  // ---- pipeline: issue-early loads (T14), double-buffered LDS, 1 barrier/subchunk ----
  LOAD(0);
  WRITE(0);
  __syncthreads();
  for (int sc = 0; sc < NSUB; ++sc) {
    if (sc + 1 < NSUB) LOAD(sc + 1);
    COMPUTE(sc & 1);
    if (sc + 1 < NSUB) WRITE((sc + 1) & 1);
    __syncthreads();
  }

  // ---- epilogue: store normalized f16 partials + (m,l) ----
  float rl = 1.0f / lrun;
  float rlq[16];
#pragma unroll
  for (int i = 0; i < 16; ++i)
    rlq[i] = __shfl(rl, (i & 3) + 8 * (i >> 2) + 4 * g2);
  _Float16* base = pctx + (size_t)(ks * NB + b) * TQ * HD;
#pragma unroll
  for (int ht = 0; ht < 4; ++ht) {
    int h = wh * 128 + ht * 32 + l31;
#pragma unroll
    for (int i = 0; i < 16; ++i) {
      int qn = wq * 32 + (i & 3) + 8 * (i >> 2) + 4 * g2;
      base[(size_t)qn * HD + h] = (_Float16)(ctx[ht][i] * rlq[i]);
    }
  }
  if (wh == 0 && g2 == 0) {
    float* mp = pml + ((size_t)ks * (NB * TQ) + b * TQ + wq * 32 + l31) * 2;
    mp[0] = mrun;
    mp[1] = lrun;
  }
}

__global__ __launch_bounds__(256) void attn_combine(
    const _Float16* __restrict__ pctx, const float* __restrict__ pml,
    float* __restrict__ out) {
  const int bq = blockIdx.x; // b*128+q
  const int h = threadIdx.x;
  float mv[KSPLIT], lvv[KSPLIT];
  float M = -1e30f;
#pragma unroll
  for (int i = 0; i < KSPLIT; ++i) {
    const float* mp = pml + ((size_t)i * (NB * TQ) + bq) * 2;
    mv[i] = mp[0];
    lvv[i] = mp[1];
    M = fmaxf(M, mv[i]);
  }
  float ssum = 0.f, acc = 0.f;
#pragma unroll
  for (int i = 0; i < KSPLIT; ++i) {
    float w = lvv[i] * __expf(mv[i] - M);
    ssum += w;
    acc += w * (float)pctx[((size_t)i * (NB * TQ) + bq) * HD + h];
  }
  out[(size_t)bq * HD + h] = acc / ssum;
}

extern "C" void kernel_launch(void* const* d_in, const int* in_sizes, int n_in,
                              void* d_out, int out_size, void* d_ws, size_t ws_size,
                              hipStream_t stream) {
  const float* enc = (const float*)d_in[0];
  const float* dec = (const float*)d_in[1];
  float* out = (float*)d_out;
  _Float16* pctx = (_Float16*)d_ws;
  float* pml = (float*)((unsigned char*)d_ws +
                        (size_t)KSPLIT * NB * TQ * HD * sizeof(_Float16));
  hipLaunchKernelGGL(attn_main, dim3(NB * KSPLIT), dim3(512), 0, stream,
                     enc, dec, pctx, pml);
  hipLaunchKernelGGL(attn_combine, dim3(NB * TQ), dim3(256), 0, stream,
                     pctx, pml, out);
}